// Round 3
// baseline (8437.019 us; speedup 1.0000x reference)
//
#include <hip/hip_runtime.h>
#include <cstdint>
#include <cstddef>

// Problem constants
#define Bb   128
#define Tt   500
#define INn  306
#define Hh   512
#define GRID 128
#define BH   (Bb * Hh)              // 65536 u16 per plane-slot

typedef short bf16x8 __attribute__((ext_vector_type(8)));
typedef float f32x4  __attribute__((ext_vector_type(4)));
typedef unsigned short u16t;

union F8 { bf16x8 v; uint4 q; unsigned u[4]; u16t s[8]; };

__device__ __forceinline__ float bf2f(u16t h) {
  unsigned u = ((unsigned)h) << 16;
  return __builtin_bit_cast(float, u);
}
__device__ __forceinline__ u16t f2bf(float f) {
  unsigned u = __builtin_bit_cast(unsigned, f);
  unsigned r = u + 0x7fffu + ((u >> 16) & 1u);   // RNE (finite inputs only)
  return (u16t)(r >> 16);
}
__device__ __forceinline__ void splitRNE(float v, u16t& hi, u16t& lo) {
  hi = f2bf(v);
  lo = f2bf(v - bf2f(hi));
}
__device__ __forceinline__ void splitTR(float v, u16t& hi, u16t& lo) {
  unsigned u = __builtin_bit_cast(unsigned, v);
  hi = (u16t)(u >> 16);
  float hf = __builtin_bit_cast(float, u & 0xFFFF0000u);
  lo = (u16t)(__builtin_bit_cast(unsigned, v - hf) >> 16);
}
__device__ __forceinline__ f32x4 MF(const F8& a, const F8& b, f32x4 c) {
  return __builtin_amdgcn_mfma_f32_16x16x32_bf16(a.v, b.v, c, 0, 0, 0);
}

// Coherent agent-scope store (global_store_* ... sc1): write-through past the
// non-coherent per-XCD L2. Counts toward vmcnt, so s_waitcnt vmcnt(0) drains it.
__device__ __forceinline__ void stsh(u16t* p, u16t v) {
  __hip_atomic_store(p, v, __ATOMIC_RELAXED, __HIP_MEMORY_SCOPE_AGENT);
}
__device__ __forceinline__ void stw(unsigned* p, unsigned v) {
  __hip_atomic_store(p, v, __ATOMIC_RELAXED, __HIP_MEMORY_SCOPE_AGENT);
}
// Equality-poll a round stamp. Stamps are 1..Tt, never 0, so poisoned (or
// zeroed) workspace never pre-matches; re-poison between iterations resets.
__device__ __forceinline__ void poll(unsigned* p, unsigned v) {
  while (__hip_atomic_load(p, __ATOMIC_RELAXED, __HIP_MEMORY_SCOPE_AGENT) != v)
    __builtin_amdgcn_s_sleep(1);
}

// ---------------------------------------------------------------------------
// Dataflow sync protocol (replaces the lockstep 16-WG leader barrier):
//   Per group g: 16 subs x 2-slot u32 flag ring at ws + g*128 (128 B total —
//   byte-identical footprint to the proven baseline; h planes at ws+1024).
//   Producer of round t stores stamp (t+1) into slot (t&1) AFTER
//   s_waitcnt vmcnt(0) drains its sc1 h-stores (release). Consumers poll
//   exact stamps, then buffer_inv sc1 (acquire).
//     L0 sub j @ t: flags0[i][(t-1)&1]==t   for all i (h0[t-1])        t>=1
//                   flags1[i][(t-2)&1]==t-1 for all i (back-pressure:
//                   all L1 done reading h0[t-2] => h0 slot t&1 free)   t>=2
//     L1 sub j @ t: flags0[i][t&1]==t+1     for all i (h0[t])
//                   flags1[i][(t-1)&1]==t   for all i (h1[t-1]; also
//                   proves h1 slot t&1 = h1[t-2]'s slot is free)       t>=1
//   Depth-2 ring safety: a producer only overwrites stamp t+1 (with t+3)
//   after gates prove every reader of t+1 completed its round; a reader
//   can't miss its stamp because the overwriting round transitively waits
//   on that reader. Deadlock-free: gates form a well-founded order
//   {L0@t <- L0@t-1, L1@t-2}, {L1@t <- L0@t, L1@t-1}.
//   t==0 skips the hh MFMA loops (h == 0), so no zero-init phase is needed.
// ---------------------------------------------------------------------------

__global__ __launch_bounds__(256, 1) void rnn_all(
    const float* x,
    const float* Wih0, const float* Whh0, const float* bih0, const float* bhh0,
    const float* Wih1, const float* Whh1, const float* bih1, const float* bhh1,
    const float* Wfc,  const float* bfc,
    float* out, unsigned char* ws)
{
  const int wg   = blockIdx.x;
  const int g    = wg >> 4;            // row-group 0..7 (16 batch rows each)
  const int sub  = wg & 15;            // 0..7 = L0 col-slices, 8..15 = L1
  const int tid  = threadIdx.x;
  const int lane = tid & 63;
  const int wave = tid >> 6;
  const int l15  = lane & 15;
  const int quad = lane >> 4;

  // flags: group g at ws + g*128; sub k slots at fl[k*2 + (t&1)]
  unsigned* fl = (unsigned*)(ws + (size_t)g * 128);
  u16t* hbase = (u16t*)(ws + 1024);
  u16t* h0hi = hbase;                  // [2][128][512] each plane
  u16t* h0lo = hbase + 2 * BH;
  u16t* h1hi = hbase + 4 * BH;
  u16t* h1lo = hbase + 6 * BH;

  // Tiling: rows = g*16..g*16+15; cols = 64 per WG (wave*16 within).
  const bool isL0 = (sub < 8);
  const int Mb    = g * 16;
  const int Jb    = (isL0 ? sub : sub - 8) * 64;
  const int jn    = Jb + wave * 16 + l15;     // output col / B-row
  const int rowA  = Mb + l15;                 // A-row this lane loads
  const int mOutB = Mb + quad * 4;            // C/D: row = quad*4 + r

  if (isL0) {
    // ---------------- Layer 0 ----------------
    F8 Bxh[10], Bxl[10], Bhh[16], Bhl[16];
#pragma unroll
    for (int kc = 0; kc < 10; ++kc) {
#pragma unroll
      for (int e = 0; e < 8; ++e) {
        const int k = kc * 32 + quad * 8 + e;
        float v = (k < INn) ? Wih0[(size_t)jn * INn + k] : 0.f;
        splitRNE(v, Bxh[kc].s[e], Bxl[kc].s[e]);
      }
    }
#pragma unroll
    for (int kc = 0; kc < 16; ++kc) {
      const float* wr = Whh0 + (size_t)jn * Hh + kc * 32 + quad * 8;
#pragma unroll
      for (int e = 0; e < 8; ++e)
        splitRNE(wr[e], Bhh[kc].s[e], Bhl[kc].s[e]);
    }
    const float bv = bih0[jn] + bhh0[jn];

    for (int t = 0; t < Tt; ++t) {
      // ---- x[t] prep first: overlaps the gating polls / peers' drains.
      F8 xh[10], xl[10];
      {
        const float* xr = x + ((size_t)rowA * Tt + t) * INn;  // 8B-aligned
#pragma unroll
        for (int kc = 0; kc < 10; ++kc) {
          const int kb = kc * 32 + quad * 8;
          float v[8];
          if (kc < 9) {
            const float2* p = (const float2*)(xr + kb);
#pragma unroll
            for (int h2 = 0; h2 < 4; ++h2) {
              float2 w = p[h2];
              v[2 * h2] = w.x; v[2 * h2 + 1] = w.y;
            }
          } else {
#pragma unroll
            for (int e = 0; e < 8; ++e)
              v[e] = (kb + e < INn) ? xr[kb + e] : 0.f;
          }
#pragma unroll
          for (int e = 0; e < 8; ++e) splitTR(v[e], xh[kc].s[e], xl[kc].s[e]);
        }
      }

      // ---- gating (no lockstep barrier)
      if (t >= 1 && tid < 8)
        poll(fl + tid * 2 + ((t - 1) & 1), (unsigned)t);           // h0[t-1]
      if (t >= 2 && tid >= 8 && tid < 16)
        poll(fl + tid * 2 + ((t - 2) & 1), (unsigned)(t - 1));     // ring free
      __syncthreads();
      asm volatile("buffer_inv sc1" ::: "memory");   // acquire: drop stale h lines

      // ---- compute
      f32x4 ac0 = {bv, bv, bv, bv};
      f32x4 ac1 = {0.f, 0.f, 0.f, 0.f};
      f32x4 ac2 = {0.f, 0.f, 0.f, 0.f};
      if (t >= 1) {
        const int ps = (t - 1) & 1;
        const u16t* phi = h0hi + (size_t)ps * BH + (size_t)rowA * Hh + quad * 8;
        const u16t* plo = h0lo + (size_t)ps * BH + (size_t)rowA * Hh + quad * 8;
#pragma unroll
        for (int kc = 0; kc < 16; ++kc) {
          F8 ah; ah.q = *(const uint4*)(phi + kc * 32);
          F8 al; al.q = *(const uint4*)(plo + kc * 32);
          ac0 = MF(ah, Bhh[kc], ac0);
          ac1 = MF(ah, Bhl[kc], ac1);
          ac2 = MF(al, Bhh[kc], ac2);
        }
      }
#pragma unroll
      for (int kc = 0; kc < 10; ++kc) {
        ac0 = MF(xh[kc], Bxh[kc], ac0);
        ac1 = MF(xh[kc], Bxl[kc], ac1);
        ac2 = MF(xl[kc], Bxh[kc], ac2);
      }

      // ---- publish h0[t] (slot t&1), release, stamp flag
      u16t* shi = h0hi + (size_t)(t & 1) * BH;
      u16t* slo = h0lo + (size_t)(t & 1) * BH;
#pragma unroll
      for (int r = 0; r < 4; ++r) {
        const float v = tanhf(ac0[r] + ac1[r] + ac2[r]);
        u16t hb, lb; splitRNE(v, hb, lb);
        const size_t m = (size_t)(mOutB + r) * Hh;
        stsh(shi + m + jn, hb);
        stsh(slo + m + jn, lb);
      }
      asm volatile("s_waitcnt vmcnt(0)" ::: "memory");
      __syncthreads();
      if (tid == 0) stw(fl + sub * 2 + (t & 1), (unsigned)(t + 1));
    }
  } else {
    // ---------------- Layer 1 ----------------
    F8 Bih[16], Bil[16], Bh2[16], Bl2[16];
#pragma unroll
    for (int kc = 0; kc < 16; ++kc) {
      const float* w1 = Wih1 + (size_t)jn * Hh + kc * 32 + quad * 8;
      const float* w2 = Whh1 + (size_t)jn * Hh + kc * 32 + quad * 8;
#pragma unroll
      for (int e = 0; e < 8; ++e) {
        splitRNE(w1[e], Bih[kc].s[e], Bil[kc].s[e]);
        splitRNE(w2[e], Bh2[kc].s[e], Bl2[kc].s[e]);
      }
    }
    const float bv = bih1[jn] + bhh1[jn];

    for (int t = 0; t < Tt; ++t) {
      // ---- gating: h0[t] from the 8 L0 subs, h1[t-1] from the 8 L1 subs.
      if (tid < 8)
        poll(fl + tid * 2 + (t & 1), (unsigned)(t + 1));           // h0[t]
      if (t >= 1 && tid >= 8 && tid < 16)
        poll(fl + tid * 2 + ((t - 1) & 1), (unsigned)t);           // h1[t-1]
      __syncthreads();
      asm volatile("buffer_inv sc1" ::: "memory");

      const int s0s = t & 1;
      const u16t* p0h = h0hi + (size_t)s0s * BH + (size_t)rowA * Hh + quad * 8;
      const u16t* p0l = h0lo + (size_t)s0s * BH + (size_t)rowA * Hh + quad * 8;
      f32x4 ac0 = {bv, bv, bv, bv};
      f32x4 ac1 = {0.f, 0.f, 0.f, 0.f};
      f32x4 ac2 = {0.f, 0.f, 0.f, 0.f};
#pragma unroll
      for (int kc = 0; kc < 16; ++kc) {
        F8 ah; ah.q = *(const uint4*)(p0h + kc * 32);
        F8 al; al.q = *(const uint4*)(p0l + kc * 32);
        ac0 = MF(ah, Bih[kc], ac0);
        ac1 = MF(ah, Bil[kc], ac1);
        ac2 = MF(al, Bih[kc], ac2);
      }
      if (t >= 1) {
        const int s1r = (t - 1) & 1;     // h1[t-1] slot
        const u16t* p1h = h1hi + (size_t)s1r * BH + (size_t)rowA * Hh + quad * 8;
        const u16t* p1l = h1lo + (size_t)s1r * BH + (size_t)rowA * Hh + quad * 8;
#pragma unroll
        for (int kc = 0; kc < 16; ++kc) {
          F8 ah; ah.q = *(const uint4*)(p1h + kc * 32);
          F8 al; al.q = *(const uint4*)(p1l + kc * 32);
          ac0 = MF(ah, Bh2[kc], ac0);
          ac1 = MF(ah, Bl2[kc], ac1);
          ac2 = MF(al, Bh2[kc], ac2);
        }
      }

      // ---- publish h1[t] (slot t&1), release, stamp flag
      u16t* shi = h1hi + (size_t)(t & 1) * BH;
      u16t* slo = h1lo + (size_t)(t & 1) * BH;
#pragma unroll
      for (int r = 0; r < 4; ++r) {
        const float v = tanhf(ac0[r] + ac1[r] + ac2[r]);
        u16t hb, lb; splitRNE(v, hb, lb);
        const size_t m = (size_t)(mOutB + r) * Hh;
        stsh(shi + m + jn, hb);
        stsh(slo + m + jn, lb);
      }
      asm volatile("s_waitcnt vmcnt(0)" ::: "memory");
      __syncthreads();
      if (tid == 0) stw(fl + sub * 2 + (t & 1), (unsigned)(t + 1));
    }

    // ---- FC + softmax for this group's 16 batch rows (sub==8 only).
    // Gate on every L1 sub's final stamp, acquire, then read h1[499] (slot 1).
    if (sub == 8) {
      if (tid < 8)
        poll(fl + (8 + tid) * 2 + ((Tt - 1) & 1), (unsigned)Tt);
      __syncthreads();
      asm volatile("buffer_inv sc1" ::: "memory");
      if (tid < 16) {
        const int b = Mb + tid;
        const u16t* hh = h1hi + (size_t)((Tt - 1) & 1) * BH + (size_t)b * Hh;
        const u16t* hl = h1lo + (size_t)((Tt - 1) & 1) * BH + (size_t)b * Hh;
        float acc[4] = {bfc[0], bfc[1], bfc[2], bfc[3]};
        for (int j = 0; j < Hh; ++j) {
          const float hv = bf2f(hh[j]) + bf2f(hl[j]);
#pragma unroll
          for (int cc = 0; cc < 4; ++cc) acc[cc] += hv * Wfc[cc * Hh + j];
        }
        const float mx = fmaxf(fmaxf(acc[0], acc[1]), fmaxf(acc[2], acc[3]));
        const float e0 = expf(acc[0] - mx), e1 = expf(acc[1] - mx);
        const float e2 = expf(acc[2] - mx), e3 = expf(acc[3] - mx);
        const float si = 1.f / (e0 + e1 + e2 + e3);
        out[b * 4 + 0] = e0 * si;
        out[b * 4 + 1] = e1 * si;
        out[b * 4 + 2] = e2 * si;
        out[b * 4 + 3] = e3 * si;
      }
    }
  }
}

extern "C" void kernel_launch(void* const* d_in, const int* in_sizes, int n_in,
                              void* d_out, int out_size, void* d_ws, size_t ws_size,
                              hipStream_t stream) {
  const float* x    = (const float*)d_in[0];
  const float* Wih0 = (const float*)d_in[1];
  const float* Whh0 = (const float*)d_in[2];
  const float* bih0 = (const float*)d_in[3];
  const float* bhh0 = (const float*)d_in[4];
  const float* Wih1 = (const float*)d_in[5];
  const float* Whh1 = (const float*)d_in[6];
  const float* bih1 = (const float*)d_in[7];
  const float* bhh1 = (const float*)d_in[8];
  const float* Wfc  = (const float*)d_in[9];
  const float* bfc  = (const float*)d_in[10];
  float* out = (float*)d_out;
  unsigned char* ws = (unsigned char*)d_ws;

  rnn_all<<<dim3(GRID), dim3(256), 0, stream>>>(
      x, Wih0, Whh0, bih0, bhh0, Wih1, Whh1, bih1, bhh1, Wfc, bfc, out, ws);
}

// Round 4
// 8351.538 us; speedup vs baseline: 1.0102x; 1.0102x over previous
//
#include <hip/hip_runtime.h>
#include <cstdint>
#include <cstddef>

// Problem constants
#define Bb   128
#define Tt   500
#define INn  306
#define Hh   512
#define GRID 128
#define BH   (Bb * Hh)              // 65536 u16 per plane-slot

typedef short bf16x8 __attribute__((ext_vector_type(8)));
typedef float f32x4  __attribute__((ext_vector_type(4)));
typedef unsigned short u16t;
typedef unsigned long long u64t;

union F8 { bf16x8 v; uint4 q; unsigned u[4]; u16t s[8]; u64t d[2]; };

__device__ __forceinline__ float bf2f(u16t h) {
  unsigned u = ((unsigned)h) << 16;
  return __builtin_bit_cast(float, u);
}
__device__ __forceinline__ u16t f2bf(float f) {
  unsigned u = __builtin_bit_cast(unsigned, f);
  unsigned r = u + 0x7fffu + ((u >> 16) & 1u);   // RNE (finite inputs only)
  return (u16t)(r >> 16);
}
__device__ __forceinline__ void splitRNE(float v, u16t& hi, u16t& lo) {
  hi = f2bf(v);
  lo = f2bf(v - bf2f(hi));
}
__device__ __forceinline__ void splitTR(float v, u16t& hi, u16t& lo) {
  unsigned u = __builtin_bit_cast(unsigned, v);
  hi = (u16t)(u >> 16);
  float hf = __builtin_bit_cast(float, u & 0xFFFF0000u);
  lo = (u16t)(__builtin_bit_cast(unsigned, v - hf) >> 16);
}
__device__ __forceinline__ f32x4 MF(const F8& a, const F8& b, f32x4 c) {
  return __builtin_amdgcn_mfma_f32_16x16x32_bf16(a.v, b.v, c, 0, 0, 0);
}

// Coherent agent-scope store (global_store_* ... sc1): write-through past the
// non-coherent per-XCD L2. Counts toward vmcnt, so s_waitcnt vmcnt(0) drains it.
__device__ __forceinline__ void stsh(u16t* p, u16t v) {
  __hip_atomic_store(p, v, __ATOMIC_RELAXED, __HIP_MEMORY_SCOPE_AGENT);
}
__device__ __forceinline__ void stw(unsigned* p, unsigned v) {
  __hip_atomic_store(p, v, __ATOMIC_RELAXED, __HIP_MEMORY_SCOPE_AGENT);
}
// Coherent agent-scope 8B load (global_load_dwordx2 ... sc1): bypasses the
// possibly-stale local L2 and reads the coherence point. Same primitive the
// flag polls use — proven to observe remote sc1 stores without buffer_inv.
__device__ __forceinline__ u64t ld8(const void* p) {
  return __hip_atomic_load((const u64t*)p, __ATOMIC_RELAXED,
                           __HIP_MEMORY_SCOPE_AGENT);
}
// Equality-poll a round stamp. Stamps are 1..Tt, never 0, so poisoned (or
// zeroed) workspace never pre-matches; re-poison between iterations resets.
__device__ __forceinline__ void poll(unsigned* p, unsigned v) {
  while (__hip_atomic_load(p, __ATOMIC_RELAXED, __HIP_MEMORY_SCOPE_AGENT) != v)
    __builtin_amdgcn_s_sleep(1);
}

// ---------------------------------------------------------------------------
// Dataflow sync protocol (same as round 3 — proven correct):
//   Per group g: 16 subs x 2-slot u32 flag ring at ws + g*128 (128 B).
//   Producer of round t: sc1 h-stores -> s_waitcnt vmcnt(0) (release) ->
//   stamp (t+1) into slot (t&1). Consumers poll exact stamps, then read h
//   with agent-scope sc1 loads (NO buffer_inv — this round's change: the
//   per-round full-L2 invalidate was the prime suspect for the 16.8 us/round
//   floor; per-access coherent loads give identical visibility without the
//   invalidation storm, and keep x/weights L2-resident).
//     L0 sub j @ t: flags0[i][(t-1)&1]==t   for all i (h0[t-1])        t>=1
//                   flags1[i][(t-2)&1]==t-1 for all i (back-pressure)  t>=2
//     L1 sub j @ t: flags0[i][t&1]==t+1     for all i (h0[t])
//                   flags1[i][(t-1)&1]==t   for all i (h1[t-1])        t>=1
//   t==0 skips the hh MFMA loops (h == 0), so no zero-init phase is needed.
//   Footprint: 1024 B flags + 1.00 MiB h state (byte-identical to baseline).
// ---------------------------------------------------------------------------

__global__ __launch_bounds__(256, 1) void rnn_all(
    const float* x,
    const float* Wih0, const float* Whh0, const float* bih0, const float* bhh0,
    const float* Wih1, const float* Whh1, const float* bih1, const float* bhh1,
    const float* Wfc,  const float* bfc,
    float* out, unsigned char* ws)
{
  const int wg   = blockIdx.x;
  const int g    = wg >> 4;            // row-group 0..7 (16 batch rows each)
  const int sub  = wg & 15;            // 0..7 = L0 col-slices, 8..15 = L1
  const int tid  = threadIdx.x;
  const int lane = tid & 63;
  const int wave = tid >> 6;
  const int l15  = lane & 15;
  const int quad = lane >> 4;

  // flags: group g at ws + g*128; sub k slots at fl[k*2 + (t&1)]
  unsigned* fl = (unsigned*)(ws + (size_t)g * 128);
  u16t* hbase = (u16t*)(ws + 1024);
  u16t* h0hi = hbase;                  // [2][128][512] each plane
  u16t* h0lo = hbase + 2 * BH;
  u16t* h1hi = hbase + 4 * BH;
  u16t* h1lo = hbase + 6 * BH;

  // Tiling: rows = g*16..g*16+15; cols = 64 per WG (wave*16 within).
  const bool isL0 = (sub < 8);
  const int Mb    = g * 16;
  const int Jb    = (isL0 ? sub : sub - 8) * 64;
  const int jn    = Jb + wave * 16 + l15;     // output col / B-row
  const int rowA  = Mb + l15;                 // A-row this lane loads
  const int mOutB = Mb + quad * 4;            // C/D: row = quad*4 + r

  if (isL0) {
    // ---------------- Layer 0 ----------------
    F8 Bxh[10], Bxl[10], Bhh[16], Bhl[16];
#pragma unroll
    for (int kc = 0; kc < 10; ++kc) {
#pragma unroll
      for (int e = 0; e < 8; ++e) {
        const int k = kc * 32 + quad * 8 + e;
        float v = (k < INn) ? Wih0[(size_t)jn * INn + k] : 0.f;
        splitRNE(v, Bxh[kc].s[e], Bxl[kc].s[e]);
      }
    }
#pragma unroll
    for (int kc = 0; kc < 16; ++kc) {
      const float* wr = Whh0 + (size_t)jn * Hh + kc * 32 + quad * 8;
#pragma unroll
      for (int e = 0; e < 8; ++e)
        splitRNE(wr[e], Bhh[kc].s[e], Bhl[kc].s[e]);
    }
    const float bv = bih0[jn] + bhh0[jn];

    for (int t = 0; t < Tt; ++t) {
      // ---- x[t] prep first: overlaps the gating polls / peers' drains.
      F8 xh[10], xl[10];
      {
        const float* xr = x + ((size_t)rowA * Tt + t) * INn;  // 8B-aligned
#pragma unroll
        for (int kc = 0; kc < 10; ++kc) {
          const int kb = kc * 32 + quad * 8;
          float v[8];
          if (kc < 9) {
            const float2* p = (const float2*)(xr + kb);
#pragma unroll
            for (int h2 = 0; h2 < 4; ++h2) {
              float2 w = p[h2];
              v[2 * h2] = w.x; v[2 * h2 + 1] = w.y;
            }
          } else {
#pragma unroll
            for (int e = 0; e < 8; ++e)
              v[e] = (kb + e < INn) ? xr[kb + e] : 0.f;
          }
#pragma unroll
          for (int e = 0; e < 8; ++e) splitTR(v[e], xh[kc].s[e], xl[kc].s[e]);
        }
      }

      // ---- gating (no lockstep barrier, no buffer_inv)
      if (t >= 1 && tid < 8)
        poll(fl + tid * 2 + ((t - 1) & 1), (unsigned)t);           // h0[t-1]
      if (t >= 2 && tid >= 8 && tid < 16)
        poll(fl + tid * 2 + ((t - 2) & 1), (unsigned)(t - 1));     // ring free
      __syncthreads();

      // ---- compute
      f32x4 ac0 = {bv, bv, bv, bv};
      f32x4 ac1 = {0.f, 0.f, 0.f, 0.f};
      f32x4 ac2 = {0.f, 0.f, 0.f, 0.f};
      if (t >= 1) {
        const int ps = (t - 1) & 1;
        const u16t* phi = h0hi + (size_t)ps * BH + (size_t)rowA * Hh + quad * 8;
        const u16t* plo = h0lo + (size_t)ps * BH + (size_t)rowA * Hh + quad * 8;
#pragma unroll
        for (int kc = 0; kc < 16; ++kc) {
          F8 ah, al;
          ah.d[0] = ld8(phi + kc * 32);  ah.d[1] = ld8(phi + kc * 32 + 4);
          al.d[0] = ld8(plo + kc * 32);  al.d[1] = ld8(plo + kc * 32 + 4);
          ac0 = MF(ah, Bhh[kc], ac0);
          ac1 = MF(ah, Bhl[kc], ac1);
          ac2 = MF(al, Bhh[kc], ac2);
        }
      }
#pragma unroll
      for (int kc = 0; kc < 10; ++kc) {
        ac0 = MF(xh[kc], Bxh[kc], ac0);
        ac1 = MF(xh[kc], Bxl[kc], ac1);
        ac2 = MF(xl[kc], Bxh[kc], ac2);
      }

      // ---- publish h0[t] (slot t&1), release, stamp flag
      u16t* shi = h0hi + (size_t)(t & 1) * BH;
      u16t* slo = h0lo + (size_t)(t & 1) * BH;
#pragma unroll
      for (int r = 0; r < 4; ++r) {
        const float v = tanhf(ac0[r] + ac1[r] + ac2[r]);
        u16t hb, lb; splitRNE(v, hb, lb);
        const size_t m = (size_t)(mOutB + r) * Hh;
        stsh(shi + m + jn, hb);
        stsh(slo + m + jn, lb);
      }
      asm volatile("s_waitcnt vmcnt(0)" ::: "memory");
      __syncthreads();
      if (tid == 0) stw(fl + sub * 2 + (t & 1), (unsigned)(t + 1));
    }
  } else {
    // ---------------- Layer 1 ----------------
    F8 Bih[16], Bil[16], Bh2[16], Bl2[16];
#pragma unroll
    for (int kc = 0; kc < 16; ++kc) {
      const float* w1 = Wih1 + (size_t)jn * Hh + kc * 32 + quad * 8;
      const float* w2 = Whh1 + (size_t)jn * Hh + kc * 32 + quad * 8;
#pragma unroll
      for (int e = 0; e < 8; ++e) {
        splitRNE(w1[e], Bih[kc].s[e], Bil[kc].s[e]);
        splitRNE(w2[e], Bh2[kc].s[e], Bl2[kc].s[e]);
      }
    }
    const float bv = bih1[jn] + bhh1[jn];

    for (int t = 0; t < Tt; ++t) {
      // ---- gating: h0[t] from the 8 L0 subs, h1[t-1] from the 8 L1 subs.
      if (tid < 8)
        poll(fl + tid * 2 + (t & 1), (unsigned)(t + 1));           // h0[t]
      if (t >= 1 && tid >= 8 && tid < 16)
        poll(fl + tid * 2 + ((t - 1) & 1), (unsigned)t);           // h1[t-1]
      __syncthreads();

      const int s0s = t & 1;
      const u16t* p0h = h0hi + (size_t)s0s * BH + (size_t)rowA * Hh + quad * 8;
      const u16t* p0l = h0lo + (size_t)s0s * BH + (size_t)rowA * Hh + quad * 8;
      f32x4 ac0 = {bv, bv, bv, bv};
      f32x4 ac1 = {0.f, 0.f, 0.f, 0.f};
      f32x4 ac2 = {0.f, 0.f, 0.f, 0.f};
#pragma unroll
      for (int kc = 0; kc < 16; ++kc) {
        F8 ah, al;
        ah.d[0] = ld8(p0h + kc * 32);  ah.d[1] = ld8(p0h + kc * 32 + 4);
        al.d[0] = ld8(p0l + kc * 32);  al.d[1] = ld8(p0l + kc * 32 + 4);
        ac0 = MF(ah, Bih[kc], ac0);
        ac1 = MF(ah, Bil[kc], ac1);
        ac2 = MF(al, Bih[kc], ac2);
      }
      if (t >= 1) {
        const int s1r = (t - 1) & 1;     // h1[t-1] slot
        const u16t* p1h = h1hi + (size_t)s1r * BH + (size_t)rowA * Hh + quad * 8;
        const u16t* p1l = h1lo + (size_t)s1r * BH + (size_t)rowA * Hh + quad * 8;
#pragma unroll
        for (int kc = 0; kc < 16; ++kc) {
          F8 ah, al;
          ah.d[0] = ld8(p1h + kc * 32);  ah.d[1] = ld8(p1h + kc * 32 + 4);
          al.d[0] = ld8(p1l + kc * 32);  al.d[1] = ld8(p1l + kc * 32 + 4);
          ac0 = MF(ah, Bh2[kc], ac0);
          ac1 = MF(ah, Bl2[kc], ac1);
          ac2 = MF(al, Bh2[kc], ac2);
        }
      }

      // ---- publish h1[t] (slot t&1), release, stamp flag
      u16t* shi = h1hi + (size_t)(t & 1) * BH;
      u16t* slo = h1lo + (size_t)(t & 1) * BH;
#pragma unroll
      for (int r = 0; r < 4; ++r) {
        const float v = tanhf(ac0[r] + ac1[r] + ac2[r]);
        u16t hb, lb; splitRNE(v, hb, lb);
        const size_t m = (size_t)(mOutB + r) * Hh;
        stsh(shi + m + jn, hb);
        stsh(slo + m + jn, lb);
      }
      asm volatile("s_waitcnt vmcnt(0)" ::: "memory");
      __syncthreads();
      if (tid == 0) stw(fl + sub * 2 + (t & 1), (unsigned)(t + 1));
    }

    // ---- FC + softmax for this group's 16 batch rows (sub==8 only).
    // Gate on every L1 sub's final stamp, then coherent-read h1[499] (slot 1).
    if (sub == 8) {
      if (tid < 8)
        poll(fl + (8 + tid) * 2 + ((Tt - 1) & 1), (unsigned)Tt);
      __syncthreads();
      if (tid < 16) {
        const int b = Mb + tid;
        const u16t* hh = h1hi + (size_t)((Tt - 1) & 1) * BH + (size_t)b * Hh;
        const u16t* hl = h1lo + (size_t)((Tt - 1) & 1) * BH + (size_t)b * Hh;
        float acc[4] = {bfc[0], bfc[1], bfc[2], bfc[3]};
        for (int j = 0; j < Hh; j += 4) {
          const u64t wh = ld8(hh + j);
          const u64t wl = ld8(hl + j);
#pragma unroll
          for (int e = 0; e < 4; ++e) {
            const float hv = bf2f((u16t)(wh >> (16 * e)))
                           + bf2f((u16t)(wl >> (16 * e)));
#pragma unroll
            for (int cc = 0; cc < 4; ++cc) acc[cc] += hv * Wfc[cc * Hh + j + e];
          }
        }
        const float mx = fmaxf(fmaxf(acc[0], acc[1]), fmaxf(acc[2], acc[3]));
        const float e0 = expf(acc[0] - mx), e1 = expf(acc[1] - mx);
        const float e2 = expf(acc[2] - mx), e3 = expf(acc[3] - mx);
        const float si = 1.f / (e0 + e1 + e2 + e3);
        out[b * 4 + 0] = e0 * si;
        out[b * 4 + 1] = e1 * si;
        out[b * 4 + 2] = e2 * si;
        out[b * 4 + 3] = e3 * si;
      }
    }
  }
}

extern "C" void kernel_launch(void* const* d_in, const int* in_sizes, int n_in,
                              void* d_out, int out_size, void* d_ws, size_t ws_size,
                              hipStream_t stream) {
  const float* x    = (const float*)d_in[0];
  const float* Wih0 = (const float*)d_in[1];
  const float* Whh0 = (const float*)d_in[2];
  const float* bih0 = (const float*)d_in[3];
  const float* bhh0 = (const float*)d_in[4];
  const float* Wih1 = (const float*)d_in[5];
  const float* Whh1 = (const float*)d_in[6];
  const float* bih1 = (const float*)d_in[7];
  const float* bhh1 = (const float*)d_in[8];
  const float* Wfc  = (const float*)d_in[9];
  const float* bfc  = (const float*)d_in[10];
  float* out = (float*)d_out;
  unsigned char* ws = (unsigned char*)d_ws;

  rnn_all<<<dim3(GRID), dim3(256), 0, stream>>>(
      x, Wih0, Whh0, bih0, bhh0, Wih1, Whh1, bih1, bhh1, Wfc, bfc, out, ws);
}

// Round 5
// 6214.419 us; speedup vs baseline: 1.3577x; 1.3439x over previous
//
#include <hip/hip_runtime.h>
#include <cstdint>
#include <cstddef>

// Problem constants
#define Bb   128
#define Tt   500
#define INn  306
#define Hh   512
#define GRID 128
#define BH32 (Bb * Hh)              // 65536 u32 per plane-slot (packed hi|lo)

typedef short bf16x8 __attribute__((ext_vector_type(8)));
typedef float f32x4  __attribute__((ext_vector_type(4)));
typedef unsigned short u16t;

union F8 { bf16x8 v; uint4 q; unsigned u[4]; u16t s[8]; };

__device__ __forceinline__ float bf2f(u16t h) {
  unsigned u = ((unsigned)h) << 16;
  return __builtin_bit_cast(float, u);
}
__device__ __forceinline__ u16t f2bf(float f) {
  unsigned u = __builtin_bit_cast(unsigned, f);
  unsigned r = u + 0x7fffu + ((u >> 16) & 1u);   // RNE (finite inputs only)
  return (u16t)(r >> 16);
}
__device__ __forceinline__ void splitRNE(float v, u16t& hi, u16t& lo) {
  hi = f2bf(v);
  lo = f2bf(v - bf2f(hi));
}
__device__ __forceinline__ void splitTR(float v, u16t& hi, u16t& lo) {
  unsigned u = __builtin_bit_cast(unsigned, v);
  hi = (u16t)(u >> 16);
  float hf = __builtin_bit_cast(float, u & 0xFFFF0000u);
  lo = (u16t)(__builtin_bit_cast(unsigned, v - hf) >> 16);
}
__device__ __forceinline__ f32x4 MF(const F8& a, const F8& b, f32x4 c) {
  return __builtin_amdgcn_mfma_f32_16x16x32_bf16(a.v, b.v, c, 0, 0, 0);
}

// Coherent agent-scope u32 store (global_store_dword ... sc1): write-through
// past the non-coherent per-XCD L2; acked at the coherence point, so
// s_waitcnt vmcnt(0) is a release drain.
__device__ __forceinline__ void stw(unsigned* p, unsigned v) {
  __hip_atomic_store(p, v, __ATOMIC_RELAXED, __HIP_MEMORY_SCOPE_AGENT);
}
// Equality-poll a round stamp. Stamps are 1..Tt, never 0, so poisoned (or
// zeroed) workspace never pre-matches; re-poison between iterations resets.
__device__ __forceinline__ void poll(unsigned* p, unsigned v) {
  while (__hip_atomic_load(p, __ATOMIC_RELAXED, __HIP_MEMORY_SCOPE_AGENT) != v)
    __builtin_amdgcn_s_sleep(1);
}

// ---------------------------------------------------------------------------
// Round-5 changes (sync protocol itself is round-3's, proven correct):
//  * h state is PACKED u32 (hi<<16|lo): 4 stw/thread instead of 8 u16 stores.
//  * Consumers stage the h tile (16 rows x 512 cols) into LDS cooperatively
//    in ONE parallel batch (8 dwordx4/thread) after gate + buffer_inv, then
//    feed MFMA via swizzled ds_read_b128. Kills the 4x cross-wave redundant
//    L3 reads and the VGPR-starved serial load batches of rounds 0-4.
//  * Drain hoisting: the vmcnt(0) release for round t-1's stores runs under
//    round t's x-prep (L0) / under the h0-flag poll (L1); the flag for t-1
//    is stored at the START of iteration t. Each WG stores its own flag
//    before polling peers -> no circular wait. All ring-overwrite windows
//    re-derived: writer of slot (t&1) is gated on flags that transitively
//    prove every reader of the overwritten value finished its STAGE phase.
//  Footprint: 1024 B flags + 1.00 MiB h (identical to the proven baseline).
// ---------------------------------------------------------------------------

// Stage one packed 16x512 tile into hi/lo u16 LDS planes (16 KiB each).
// LDS plane layout: row-major [16][1024 B], 16B chunks swizzled c^= (row&7)
// so that fragment reads (16 lanes = 16 rows at one chunk) are conflict-free.
__device__ __forceinline__ void stage_tile(const unsigned* __restrict__ gsrc,
                                           unsigned char* smHi,
                                           unsigned char* smLo, int tid) {
  const int row = tid >> 4;            // 0..15
  const int c0  = tid & 15;
#pragma unroll
  for (int k = 0; k < 8; ++k) {
    const int cg = c0 + k * 16;        // 16B packed chunk (4 cols)
    const uint4 w = *(const uint4*)(gsrc + (size_t)row * Hh + (size_t)cg * 4);
    const unsigned hi0 = (w.y & 0xFFFF0000u) | (w.x >> 16);
    const unsigned hi1 = (w.w & 0xFFFF0000u) | (w.z >> 16);
    const unsigned lo0 = (w.y << 16) | (w.x & 0xFFFFu);
    const unsigned lo1 = (w.w << 16) | (w.z & 0xFFFFu);
    const int ch   = cg >> 1;          // 16B chunk in the u16 plane
    const int half = cg & 1;
    const size_t boff = (size_t)row * 1024 + ((size_t)(ch ^ (row & 7)) << 4)
                      + (size_t)half * 8;
    *(uint2*)(smHi + boff) = make_uint2(hi0, hi1);
    *(uint2*)(smLo + boff) = make_uint2(lo0, lo1);
  }
}
// Read one A-fragment (8 cols) for (row, kc, quad) from a staged plane.
__device__ __forceinline__ F8 fragLDS(const unsigned char* smP, int row,
                                      int kc, int quad) {
  const int c = kc * 4 + quad;
  F8 f;
  f.q = *(const uint4*)(smP + (size_t)row * 1024
                        + ((size_t)(c ^ (row & 7)) << 4));
  return f;
}

__global__ __launch_bounds__(256, 1) void rnn_all(
    const float* x,
    const float* Wih0, const float* Whh0, const float* bih0, const float* bhh0,
    const float* Wih1, const float* Whh1, const float* bih1, const float* bhh1,
    const float* Wfc,  const float* bfc,
    float* out, unsigned char* ws)
{
  const int wg   = blockIdx.x;
  const int g    = wg >> 4;            // row-group 0..7 (16 batch rows each)
  const int sub  = wg & 15;            // 0..7 = L0 col-slices, 8..15 = L1
  const int tid  = threadIdx.x;
  const int lane = tid & 63;
  const int wave = tid >> 6;
  const int l15  = lane & 15;
  const int quad = lane >> 4;

  __shared__ __align__(16) unsigned char sm[65536];
  unsigned char* smA = sm;             // h0 hi (L0/L1)
  unsigned char* smB = sm + 16384;     // h0 lo
  unsigned char* smC = sm + 32768;     // h1 hi (L1 only)
  unsigned char* smD = sm + 49152;     // h1 lo

  // flags: group g at ws + g*128; sub k slots at fl[k*2 + (t&1)]
  unsigned* fl = (unsigned*)(ws + (size_t)g * 128);
  unsigned* hb32 = (unsigned*)(ws + 1024);
  unsigned* h0p = hb32;                        // [2][128][512] packed u32
  unsigned* h1p = hb32 + (size_t)2 * BH32;     // [2][128][512]

  // Tiling: rows = g*16..g*16+15; cols = 64 per WG (wave*16 within).
  const bool isL0 = (sub < 8);
  const int Mb    = g * 16;
  const int Jb    = (isL0 ? sub : sub - 8) * 64;
  const int jn    = Jb + wave * 16 + l15;     // output col / B-row
  const int rowA  = Mb + l15;                 // A-row this lane loads
  const int mOutB = Mb + quad * 4;            // C/D: row = quad*4 + r

  if (isL0) {
    // ---------------- Layer 0 ----------------
    F8 Bxh[10], Bxl[10], Bhh[16], Bhl[16];
#pragma unroll
    for (int kc = 0; kc < 10; ++kc) {
#pragma unroll
      for (int e = 0; e < 8; ++e) {
        const int k = kc * 32 + quad * 8 + e;
        float v = (k < INn) ? Wih0[(size_t)jn * INn + k] : 0.f;
        splitRNE(v, Bxh[kc].s[e], Bxl[kc].s[e]);
      }
    }
#pragma unroll
    for (int kc = 0; kc < 16; ++kc) {
      const float* wr = Whh0 + (size_t)jn * Hh + kc * 32 + quad * 8;
#pragma unroll
      for (int e = 0; e < 8; ++e)
        splitRNE(wr[e], Bhh[kc].s[e], Bhl[kc].s[e]);
    }
    const float bv = bih0[jn] + bhh0[jn];

    for (int t = 0; t < Tt; ++t) {
      // ---- x[t] prep first: hides round t-1's store drain.
      F8 xh[10], xl[10];
      {
        const float* xr = x + ((size_t)rowA * Tt + t) * INn;  // 8B-aligned
#pragma unroll
        for (int kc = 0; kc < 10; ++kc) {
          const int kb = kc * 32 + quad * 8;
          float v[8];
          if (kc < 9) {
            const float2* p = (const float2*)(xr + kb);
#pragma unroll
            for (int h2 = 0; h2 < 4; ++h2) {
              float2 w = p[h2];
              v[2 * h2] = w.x; v[2 * h2 + 1] = w.y;
            }
          } else {
#pragma unroll
            for (int e = 0; e < 8; ++e)
              v[e] = (kb + e < INn) ? xr[kb + e] : 0.f;
          }
#pragma unroll
          for (int e = 0; e < 8; ++e) splitTR(v[e], xh[kc].s[e], xl[kc].s[e]);
        }
      }

      // ---- release round t-1 (drain overlapped the x-prep above), flag,
      //      then gate round t. Own flag stored BEFORE peer polls: no cycle.
      if (t >= 1) {
        asm volatile("s_waitcnt vmcnt(0)" ::: "memory");
        __syncthreads();
        if (tid == 0) stw(fl + sub * 2 + ((t - 1) & 1), (unsigned)t);
      }
      if (t >= 1 && tid < 8)
        poll(fl + tid * 2 + ((t - 1) & 1), (unsigned)t);           // h0[t-1]
      if (t >= 2 && tid >= 8 && tid < 16)
        poll(fl + tid * 2 + ((t - 2) & 1), (unsigned)(t - 1));     // ring free
      __syncthreads();
      asm volatile("buffer_inv sc1" ::: "memory");   // acquire

      // ---- cooperative stage of h0[t-1] (one parallel batch), then compute
      if (t >= 1) {
        stage_tile(h0p + (size_t)((t - 1) & 1) * BH32 + (size_t)Mb * Hh,
                   smA, smB, tid);
        __syncthreads();
      }
      f32x4 ac0 = {bv, bv, bv, bv};
      f32x4 ac1 = {0.f, 0.f, 0.f, 0.f};
      f32x4 ac2 = {0.f, 0.f, 0.f, 0.f};
      if (t >= 1) {
#pragma unroll
        for (int kc = 0; kc < 16; ++kc) {
          F8 ah = fragLDS(smA, l15, kc, quad);
          F8 al = fragLDS(smB, l15, kc, quad);
          ac0 = MF(ah, Bhh[kc], ac0);
          ac1 = MF(ah, Bhl[kc], ac1);
          ac2 = MF(al, Bhh[kc], ac2);
        }
      }
#pragma unroll
      for (int kc = 0; kc < 10; ++kc) {
        ac0 = MF(xh[kc], Bxh[kc], ac0);
        ac1 = MF(xh[kc], Bxl[kc], ac1);
        ac2 = MF(xl[kc], Bxh[kc], ac2);
      }

      // ---- publish h0[t] packed (slot t&1); drain deferred to next iter
      unsigned* dst = h0p + (size_t)(t & 1) * BH32;
#pragma unroll
      for (int r = 0; r < 4; ++r) {
        const float v = tanhf(ac0[r] + ac1[r] + ac2[r]);
        u16t hb, lb; splitRNE(v, hb, lb);
        stw(dst + (size_t)(mOutB + r) * Hh + jn,
            ((unsigned)hb << 16) | (unsigned)lb);
      }
    }
    asm volatile("s_waitcnt vmcnt(0)" ::: "memory");
    __syncthreads();
    if (tid == 0) stw(fl + sub * 2 + ((Tt - 1) & 1), (unsigned)Tt);
  } else {
    // ---------------- Layer 1 ----------------
    F8 Bih[16], Bil[16], Bh2[16], Bl2[16];
#pragma unroll
    for (int kc = 0; kc < 16; ++kc) {
      const float* w1 = Wih1 + (size_t)jn * Hh + kc * 32 + quad * 8;
      const float* w2 = Whh1 + (size_t)jn * Hh + kc * 32 + quad * 8;
#pragma unroll
      for (int e = 0; e < 8; ++e) {
        splitRNE(w1[e], Bih[kc].s[e], Bil[kc].s[e]);
        splitRNE(w2[e], Bh2[kc].s[e], Bl2[kc].s[e]);
      }
    }
    const float bv = bih1[jn] + bhh1[jn];

    for (int t = 0; t < Tt; ++t) {
      // ---- poll L0's h0[t] flag first: round t-1's store drain completes
      //      in the background while wave 0 spins here.
      if (tid < 8)
        poll(fl + tid * 2 + (t & 1), (unsigned)(t + 1));           // h0[t]
      if (t >= 1) {
        asm volatile("s_waitcnt vmcnt(0)" ::: "memory");
        __syncthreads();
        if (tid == 0) stw(fl + sub * 2 + ((t - 1) & 1), (unsigned)t);
        if (tid >= 8 && tid < 16)
          poll(fl + tid * 2 + ((t - 1) & 1), (unsigned)t);         // h1[t-1]
      }
      __syncthreads();
      asm volatile("buffer_inv sc1" ::: "memory");   // acquire

      // ---- cooperative stage (one parallel batch over both tiles)
      stage_tile(h0p + (size_t)(t & 1) * BH32 + (size_t)Mb * Hh, smA, smB, tid);
      if (t >= 1)
        stage_tile(h1p + (size_t)((t - 1) & 1) * BH32 + (size_t)Mb * Hh,
                   smC, smD, tid);
      __syncthreads();

      f32x4 ac0 = {bv, bv, bv, bv};
      f32x4 ac1 = {0.f, 0.f, 0.f, 0.f};
      f32x4 ac2 = {0.f, 0.f, 0.f, 0.f};
#pragma unroll
      for (int kc = 0; kc < 16; ++kc) {
        F8 ah = fragLDS(smA, l15, kc, quad);
        F8 al = fragLDS(smB, l15, kc, quad);
        ac0 = MF(ah, Bih[kc], ac0);
        ac1 = MF(ah, Bil[kc], ac1);
        ac2 = MF(al, Bih[kc], ac2);
      }
      if (t >= 1) {
#pragma unroll
        for (int kc = 0; kc < 16; ++kc) {
          F8 ah = fragLDS(smC, l15, kc, quad);
          F8 al = fragLDS(smD, l15, kc, quad);
          ac0 = MF(ah, Bh2[kc], ac0);
          ac1 = MF(ah, Bl2[kc], ac1);
          ac2 = MF(al, Bh2[kc], ac2);
        }
      }

      // ---- publish h1[t] packed (slot t&1); drain deferred to next iter
      unsigned* dst = h1p + (size_t)(t & 1) * BH32;
#pragma unroll
      for (int r = 0; r < 4; ++r) {
        const float v = tanhf(ac0[r] + ac1[r] + ac2[r]);
        u16t hb, lb; splitRNE(v, hb, lb);
        stw(dst + (size_t)(mOutB + r) * Hh + jn,
            ((unsigned)hb << 16) | (unsigned)lb);
      }
    }
    asm volatile("s_waitcnt vmcnt(0)" ::: "memory");
    __syncthreads();
    if (tid == 0) stw(fl + sub * 2 + ((Tt - 1) & 1), (unsigned)Tt);

    // ---- FC + softmax for this group's 16 batch rows (sub==8 only).
    if (sub == 8) {
      if (tid < 8)
        poll(fl + (8 + tid) * 2 + ((Tt - 1) & 1), (unsigned)Tt);
      __syncthreads();
      asm volatile("buffer_inv sc1" ::: "memory");
      if (tid < 16) {
        const int b = Mb + tid;
        const unsigned* hp = h1p + (size_t)((Tt - 1) & 1) * BH32
                           + (size_t)b * Hh;
        float acc[4] = {bfc[0], bfc[1], bfc[2], bfc[3]};
        for (int j = 0; j < Hh; ++j) {
          const unsigned w = hp[j];
          const float hv = bf2f((u16t)(w >> 16)) + bf2f((u16t)(w & 0xFFFFu));
#pragma unroll
          for (int cc = 0; cc < 4; ++cc) acc[cc] += hv * Wfc[cc * Hh + j];
        }
        const float mx = fmaxf(fmaxf(acc[0], acc[1]), fmaxf(acc[2], acc[3]));
        const float e0 = expf(acc[0] - mx), e1 = expf(acc[1] - mx);
        const float e2 = expf(acc[2] - mx), e3 = expf(acc[3] - mx);
        const float si = 1.f / (e0 + e1 + e2 + e3);
        out[b * 4 + 0] = e0 * si;
        out[b * 4 + 1] = e1 * si;
        out[b * 4 + 2] = e2 * si;
        out[b * 4 + 3] = e3 * si;
      }
    }
  }
}

extern "C" void kernel_launch(void* const* d_in, const int* in_sizes, int n_in,
                              void* d_out, int out_size, void* d_ws, size_t ws_size,
                              hipStream_t stream) {
  const float* x    = (const float*)d_in[0];
  const float* Wih0 = (const float*)d_in[1];
  const float* Whh0 = (const float*)d_in[2];
  const float* bih0 = (const float*)d_in[3];
  const float* bhh0 = (const float*)d_in[4];
  const float* Wih1 = (const float*)d_in[5];
  const float* Whh1 = (const float*)d_in[6];
  const float* bih1 = (const float*)d_in[7];
  const float* bhh1 = (const float*)d_in[8];
  const float* Wfc  = (const float*)d_in[9];
  const float* bfc  = (const float*)d_in[10];
  float* out = (float*)d_out;
  unsigned char* ws = (unsigned char*)d_ws;

  rnn_all<<<dim3(GRID), dim3(256), 0, stream>>>(
      x, Wih0, Whh0, bih0, bhh0, Wih1, Whh1, bih1, bhh1, Wfc, bfc, out, ws);
}

// Round 7
// 5149.646 us; speedup vs baseline: 1.6384x; 1.2068x over previous
//
#include <hip/hip_runtime.h>
#include <cstdint>
#include <cstddef>

// Problem constants
#define Bb   128
#define Tt   500
#define INn  306
#define Hh   512
#define GRID 128
#define BH32 (Bb * Hh)              // 65536 u32 per plane-slot (packed hi|lo)

typedef short bf16x8 __attribute__((ext_vector_type(8)));
typedef float f32x4  __attribute__((ext_vector_type(4)));
typedef unsigned u32x4 __attribute__((ext_vector_type(4)));
typedef unsigned short u16t;

union F8 { bf16x8 v; uint4 q; unsigned u[4]; u16t s[8]; };

__device__ __forceinline__ float bf2f(u16t h) {
  unsigned u = ((unsigned)h) << 16;
  return __builtin_bit_cast(float, u);
}
__device__ __forceinline__ u16t f2bf(float f) {
  unsigned u = __builtin_bit_cast(unsigned, f);
  unsigned r = u + 0x7fffu + ((u >> 16) & 1u);   // RNE (finite inputs only)
  return (u16t)(r >> 16);
}
__device__ __forceinline__ void splitRNE(float v, u16t& hi, u16t& lo) {
  hi = f2bf(v);
  lo = f2bf(v - bf2f(hi));
}
__device__ __forceinline__ void splitTR(float v, u16t& hi, u16t& lo) {
  unsigned u = __builtin_bit_cast(unsigned, v);
  hi = (u16t)(u >> 16);
  float hf = __builtin_bit_cast(float, u & 0xFFFF0000u);
  lo = (u16t)(__builtin_bit_cast(unsigned, v - hf) >> 16);
}
__device__ __forceinline__ f32x4 MF(const F8& a, const F8& b, f32x4 c) {
  return __builtin_amdgcn_mfma_f32_16x16x32_bf16(a.v, b.v, c, 0, 0, 0);
}

// Agent-scope (sc1) primitives: write-through past the non-coherent per-XCD
// L2 to the device coherence point. Used by SAFE path + one-time verdict.
__device__ __forceinline__ void stw(unsigned* p, unsigned v) {
  __hip_atomic_store(p, v, __ATOMIC_RELAXED, __HIP_MEMORY_SCOPE_AGENT);
}
__device__ __forceinline__ unsigned ldw(const unsigned* p) {
  return __hip_atomic_load(p, __ATOMIC_RELAXED, __HIP_MEMORY_SCOPE_AGENT);
}

// ---------------------------------------------------------------------------
// Two flavors of the proven round-5 dataflow protocol (identical gate logic):
//  FAST (all 16 WGs of the group measured on ONE XCD): exchange through the
//   XCD-shared L2. Stores = plain (CDNA vector L1 is write-through -> data
//   lands in L2, the intra-XCD coherence point). Loads = plain load preceded
//   by `buffer_inv` (L1-ONLY invalidate; cheap, local) -> miss L1, hit the
//   shared L2. vmcnt(0) drains h stores to L2 before the flag store, so
//   flag-visible implies h-visible. No sc1 traffic, no L2 invalidate: x and
//   weights stay L2-resident all 500 rounds.
//  SAFE (mixed XCDs): exact round-5 scheme (sc1 stores/loads + buffer_inv
//   sc1). Verdict is deterministic and unanimous per group.
// Gates (both paths), flag ring = 16 subs x 2 slots per group:
//   L0 sub j @ t: flags0[i][(t-1)&1]==t   all i (h0[t-1])        t>=1
//                 flags1[i][(t-2)&1]==t-1 all i (back-pressure)  t>=2
//   L1 sub j @ t: flags0[i][t&1]==t+1     all i (h0[t])
//                 flags1[i][(t-1)&1]==t   all i (h1[t-1])        t>=1
// Footprint: 1024 B flags + 1.00 MiB h (byte-identical to proven baseline).
// ---------------------------------------------------------------------------

template<bool FAST>
__device__ __forceinline__ void stf(unsigned* p, unsigned v) {
  if constexpr (FAST) *(volatile unsigned*)p = v;   // write-through L1 -> L2
  else stw(p, v);
}
template<bool FAST>
__device__ __forceinline__ void invL() {
  if constexpr (FAST) asm volatile("buffer_inv" ::: "memory");      // L1 only
  else asm volatile("buffer_inv sc1" ::: "memory");                 // L1+L2
}
template<bool FAST>
__device__ __forceinline__ void fpoll(const unsigned* p, unsigned v) {
  if constexpr (FAST) {
    for (;;) {
      asm volatile("buffer_inv" ::: "memory");      // drop stale L1 line
      if (*(const volatile unsigned*)p == v) break;
      __builtin_amdgcn_s_sleep(1);
    }
  } else {
    while (ldw(p) != v) __builtin_amdgcn_s_sleep(1);
  }
}

// Stage one packed 16x512 tile into hi/lo u16 LDS planes (16 KiB each).
// LDS layout: row-major [16][1024 B], 16B chunks swizzled c ^= (row&7).
// Caller has already executed the path-appropriate invalidate.
__device__ __forceinline__ void stage_tile(const unsigned* __restrict__ gsrc,
                                           unsigned char* smHi,
                                           unsigned char* smLo, int tid) {
  const int row = tid >> 4;            // 0..15
  const int c0  = tid & 15;
#pragma unroll
  for (int k = 0; k < 8; ++k) {
    const int cg = c0 + k * 16;        // 16B packed chunk (4 cols)
    const u32x4 w = *(const u32x4*)(gsrc + (size_t)row * Hh + (size_t)cg * 4);
    const unsigned hi0 = (w[1] & 0xFFFF0000u) | (w[0] >> 16);
    const unsigned hi1 = (w[3] & 0xFFFF0000u) | (w[2] >> 16);
    const unsigned lo0 = (w[1] << 16) | (w[0] & 0xFFFFu);
    const unsigned lo1 = (w[3] << 16) | (w[2] & 0xFFFFu);
    const int ch   = cg >> 1;          // 16B chunk in the u16 plane
    const int half = cg & 1;
    const size_t boff = (size_t)row * 1024 + ((size_t)(ch ^ (row & 7)) << 4)
                      + (size_t)half * 8;
    *(uint2*)(smHi + boff) = make_uint2(hi0, hi1);
    *(uint2*)(smLo + boff) = make_uint2(lo0, lo1);
  }
}
// Read one A-fragment (8 cols) for (row, kc, quad) from a staged plane.
__device__ __forceinline__ F8 fragLDS(const unsigned char* smP, int row,
                                      int kc, int quad) {
  const int c = kc * 4 + quad;
  F8 f;
  f.q = *(const uint4*)(smP + (size_t)row * 1024
                        + ((size_t)(c ^ (row & 7)) << 4));
  return f;
}

template<bool FAST>
__device__ void body(
    const float* x,
    const float* Wih0, const float* Whh0, const float* bih0, const float* bhh0,
    const float* Wih1, const float* Whh1, const float* bih1, const float* bhh1,
    const float* Wfc,  const float* bfc, float* out,
    unsigned* fl, unsigned* h0p, unsigned* h1p, unsigned char* sm,
    int sub, int tid, int Mb)
{
  const int lane = tid & 63;
  const int wave = tid >> 6;
  const int l15  = lane & 15;
  const int quad = lane >> 4;

  unsigned char* smA = sm;             // h0 hi
  unsigned char* smB = sm + 16384;     // h0 lo
  unsigned char* smC = sm + 32768;     // h1 hi (L1 only)
  unsigned char* smD = sm + 49152;     // h1 lo

  const bool isL0 = (sub < 8);
  const int Jb    = (isL0 ? sub : sub - 8) * 64;
  const int jn    = Jb + wave * 16 + l15;     // output col / B-row
  const int rowA  = Mb + l15;                 // A-row this lane loads
  const int mOutB = Mb + quad * 4;            // C/D: row = quad*4 + r

  if (isL0) {
    // ---------------- Layer 0 ----------------
    F8 Bxh[10], Bxl[10], Bhh[16], Bhl[16];
#pragma unroll
    for (int kc = 0; kc < 10; ++kc) {
#pragma unroll
      for (int e = 0; e < 8; ++e) {
        const int k = kc * 32 + quad * 8 + e;
        float v = (k < INn) ? Wih0[(size_t)jn * INn + k] : 0.f;
        splitRNE(v, Bxh[kc].s[e], Bxl[kc].s[e]);
      }
    }
#pragma unroll
    for (int kc = 0; kc < 16; ++kc) {
      const float* wr = Whh0 + (size_t)jn * Hh + kc * 32 + quad * 8;
#pragma unroll
      for (int e = 0; e < 8; ++e)
        splitRNE(wr[e], Bhh[kc].s[e], Bhl[kc].s[e]);
    }
    const float bv = bih0[jn] + bhh0[jn];

    for (int t = 0; t < Tt; ++t) {
      // ---- x[t] prep first: hides round t-1's store drain.
      F8 xh[10], xl[10];
      {
        const float* xr = x + ((size_t)rowA * Tt + t) * INn;  // 8B-aligned
#pragma unroll
        for (int kc = 0; kc < 10; ++kc) {
          const int kb = kc * 32 + quad * 8;
          float v[8];
          if (kc < 9) {
            const float2* p = (const float2*)(xr + kb);
#pragma unroll
            for (int h2 = 0; h2 < 4; ++h2) {
              float2 w = p[h2];
              v[2 * h2] = w.x; v[2 * h2 + 1] = w.y;
            }
          } else {
#pragma unroll
            for (int e = 0; e < 8; ++e)
              v[e] = (kb + e < INn) ? xr[kb + e] : 0.f;
          }
#pragma unroll
          for (int e = 0; e < 8; ++e) splitTR(v[e], xh[kc].s[e], xl[kc].s[e]);
        }
      }

      // ---- release round t-1 (drain overlapped x-prep), flag, gate round t
      if (t >= 1) {
        asm volatile("s_waitcnt vmcnt(0)" ::: "memory");
        __syncthreads();
        if (tid == 0) stf<FAST>(fl + sub * 2 + ((t - 1) & 1), (unsigned)t);
      }
      if (t >= 1 && tid < 8)
        fpoll<FAST>(fl + tid * 2 + ((t - 1) & 1), (unsigned)t);      // h0[t-1]
      if (t >= 2 && tid >= 8 && tid < 16)
        fpoll<FAST>(fl + tid * 2 + ((t - 2) & 1), (unsigned)(t - 1)); // ring free
      __syncthreads();
      invL<FAST>();                                  // acquire

      // ---- cooperative stage of h0[t-1], then compute
      if (t >= 1) {
        stage_tile(h0p + (size_t)((t - 1) & 1) * BH32 + (size_t)Mb * Hh,
                   smA, smB, tid);
        __syncthreads();
      }
      f32x4 ac0 = {bv, bv, bv, bv};
      f32x4 ac1 = {0.f, 0.f, 0.f, 0.f};
      f32x4 ac2 = {0.f, 0.f, 0.f, 0.f};
      if (t >= 1) {
#pragma unroll
        for (int kc = 0; kc < 16; ++kc) {
          F8 ah = fragLDS(smA, l15, kc, quad);
          F8 al = fragLDS(smB, l15, kc, quad);
          ac0 = MF(ah, Bhh[kc], ac0);
          ac1 = MF(ah, Bhl[kc], ac1);
          ac2 = MF(al, Bhh[kc], ac2);
        }
      }
#pragma unroll
      for (int kc = 0; kc < 10; ++kc) {
        ac0 = MF(xh[kc], Bxh[kc], ac0);
        ac1 = MF(xh[kc], Bxl[kc], ac1);
        ac2 = MF(xl[kc], Bxh[kc], ac2);
      }

      // ---- publish h0[t] packed (slot t&1); drain deferred to next iter
      unsigned* dst = h0p + (size_t)(t & 1) * BH32;
#pragma unroll
      for (int r = 0; r < 4; ++r) {
        const float v = tanhf(ac0[r] + ac1[r] + ac2[r]);
        u16t hb, lb; splitRNE(v, hb, lb);
        stf<FAST>(dst + (size_t)(mOutB + r) * Hh + jn,
                  ((unsigned)hb << 16) | (unsigned)lb);
      }
    }
    asm volatile("s_waitcnt vmcnt(0)" ::: "memory");
    __syncthreads();
    if (tid == 0) stf<FAST>(fl + sub * 2 + ((Tt - 1) & 1), (unsigned)Tt);
  } else {
    // ---------------- Layer 1 ----------------
    F8 Bih[16], Bil[16], Bh2[16], Bl2[16];
#pragma unroll
    for (int kc = 0; kc < 16; ++kc) {
      const float* w1 = Wih1 + (size_t)jn * Hh + kc * 32 + quad * 8;
      const float* w2 = Whh1 + (size_t)jn * Hh + kc * 32 + quad * 8;
#pragma unroll
      for (int e = 0; e < 8; ++e) {
        splitRNE(w1[e], Bih[kc].s[e], Bil[kc].s[e]);
        splitRNE(w2[e], Bh2[kc].s[e], Bl2[kc].s[e]);
      }
    }
    const float bv = bih1[jn] + bhh1[jn];

    for (int t = 0; t < Tt; ++t) {
      // ---- poll h0[t] first (round t-1's drain completes in background)
      if (tid < 8)
        fpoll<FAST>(fl + tid * 2 + (t & 1), (unsigned)(t + 1));      // h0[t]
      if (t >= 1) {
        asm volatile("s_waitcnt vmcnt(0)" ::: "memory");
        __syncthreads();
        if (tid == 0) stf<FAST>(fl + sub * 2 + ((t - 1) & 1), (unsigned)t);
        if (tid >= 8 && tid < 16)
          fpoll<FAST>(fl + tid * 2 + ((t - 1) & 1), (unsigned)t);    // h1[t-1]
      }
      __syncthreads();
      invL<FAST>();                                  // acquire

      // ---- cooperative stage
      stage_tile(h0p + (size_t)(t & 1) * BH32 + (size_t)Mb * Hh,
                 smA, smB, tid);
      if (t >= 1)
        stage_tile(h1p + (size_t)((t - 1) & 1) * BH32 + (size_t)Mb * Hh,
                   smC, smD, tid);
      __syncthreads();

      f32x4 ac0 = {bv, bv, bv, bv};
      f32x4 ac1 = {0.f, 0.f, 0.f, 0.f};
      f32x4 ac2 = {0.f, 0.f, 0.f, 0.f};
#pragma unroll
      for (int kc = 0; kc < 16; ++kc) {
        F8 ah = fragLDS(smA, l15, kc, quad);
        F8 al = fragLDS(smB, l15, kc, quad);
        ac0 = MF(ah, Bih[kc], ac0);
        ac1 = MF(ah, Bil[kc], ac1);
        ac2 = MF(al, Bih[kc], ac2);
      }
      if (t >= 1) {
#pragma unroll
        for (int kc = 0; kc < 16; ++kc) {
          F8 ah = fragLDS(smC, l15, kc, quad);
          F8 al = fragLDS(smD, l15, kc, quad);
          ac0 = MF(ah, Bh2[kc], ac0);
          ac1 = MF(ah, Bl2[kc], ac1);
          ac2 = MF(al, Bh2[kc], ac2);
        }
      }

      // ---- publish h1[t] packed (slot t&1)
      unsigned* dst = h1p + (size_t)(t & 1) * BH32;
#pragma unroll
      for (int r = 0; r < 4; ++r) {
        const float v = tanhf(ac0[r] + ac1[r] + ac2[r]);
        u16t hb, lb; splitRNE(v, hb, lb);
        stf<FAST>(dst + (size_t)(mOutB + r) * Hh + jn,
                  ((unsigned)hb << 16) | (unsigned)lb);
      }
    }
    asm volatile("s_waitcnt vmcnt(0)" ::: "memory");
    __syncthreads();
    if (tid == 0) stf<FAST>(fl + sub * 2 + ((Tt - 1) & 1), (unsigned)Tt);

    // ---- FC + softmax for this group's 16 batch rows (sub==8 only).
    if (sub == 8) {
      if (tid < 8)
        fpoll<FAST>(fl + (8 + tid) * 2 + ((Tt - 1) & 1), (unsigned)Tt);
      __syncthreads();
      invL<FAST>();
      if (tid < 16) {
        const int b = Mb + tid;
        const unsigned* hp = h1p + (size_t)((Tt - 1) & 1) * BH32
                           + (size_t)b * Hh;
        float acc[4] = {bfc[0], bfc[1], bfc[2], bfc[3]};
        for (int j = 0; j < Hh; ++j) {
          const unsigned w = *(const volatile unsigned*)(hp + j);
          const float hv = bf2f((u16t)(w >> 16)) + bf2f((u16t)(w & 0xFFFFu));
#pragma unroll
          for (int cc = 0; cc < 4; ++cc) acc[cc] += hv * Wfc[cc * Hh + j];
        }
        const float mx = fmaxf(fmaxf(acc[0], acc[1]), fmaxf(acc[2], acc[3]));
        const float e0 = expf(acc[0] - mx), e1 = expf(acc[1] - mx);
        const float e2 = expf(acc[2] - mx), e3 = expf(acc[3] - mx);
        const float si = 1.f / (e0 + e1 + e2 + e3);
        out[b * 4 + 0] = e0 * si;
        out[b * 4 + 1] = e1 * si;
        out[b * 4 + 2] = e2 * si;
        out[b * 4 + 3] = e3 * si;
      }
    }
  }
}

__global__ __launch_bounds__(256, 1) void rnn_all(
    const float* x,
    const float* Wih0, const float* Whh0, const float* bih0, const float* bhh0,
    const float* Wih1, const float* Whh1, const float* bih1, const float* bhh1,
    const float* Wfc,  const float* bfc,
    float* out, unsigned char* ws)
{
  const int wg  = blockIdx.x;
  const int g   = wg & 7;     // group = wg%8: one XCD per group IF round-robin
  const int sub = wg >> 3;    // 0..7 = L0 col-slices, 8..15 = L1
  const int tid = threadIdx.x;

  __shared__ __align__(16) unsigned char sm[65536];

  unsigned* fl  = (unsigned*)(ws + (size_t)g * 128);
  unsigned* h0p = (unsigned*)(ws + 1024);          // [2][128][512] packed u32
  unsigned* h1p = h0p + (size_t)2 * BH32;          // [2][128][512]
  const int Mb  = g * 16;

  // ---- One-time XCD co-residency verdict. Exchange table = h1 slot1 row Mb
  // cols 0..15: dead until L1's t=1 publish, which is transitively gated on
  // every WG finishing this phase (L1@t=1 needs flags1[*][0] and flags0[*][1],
  // both only stored after the owners ran their verdict). All verdict traffic
  // is sc1 (L3-coherent) regardless of mapping. Marker 0xA5C30000|xcc cannot
  // equal any stamp (1..500); masked compare tolerates poison.
  unsigned xcc;
  asm("s_getreg_b32 %0, hwreg(HW_REG_XCC_ID)" : "=s"(xcc));
  xcc &= 7u;
  unsigned* xt = h1p + (size_t)1 * BH32 + (size_t)Mb * Hh;
  if (tid == 0) stw(xt + sub, 0xA5C30000u | xcc);
  unsigned* xsh = (unsigned*)sm;                   // reuse staging LDS
  if (tid < 16) {
    unsigned v;
    do { v = ldw(xt + tid); } while ((v & 0xFFFFFFF8u) != 0xA5C30000u);
    xsh[tid] = v & 7u;
  }
  __syncthreads();
  bool fast = true;
  for (int i = 0; i < 16; ++i) fast = fast && (xsh[i] == xcc);
  __syncthreads();   // xsh dead; sm reused as staging below

  if (fast)
    body<true >(x, Wih0, Whh0, bih0, bhh0, Wih1, Whh1, bih1, bhh1,
                Wfc, bfc, out, fl, h0p, h1p, sm, sub, tid, Mb);
  else
    body<false>(x, Wih0, Whh0, bih0, bhh0, Wih1, Whh1, bih1, bhh1,
                Wfc, bfc, out, fl, h0p, h1p, sm, sub, tid, Mb);
}

extern "C" void kernel_launch(void* const* d_in, const int* in_sizes, int n_in,
                              void* d_out, int out_size, void* d_ws, size_t ws_size,
                              hipStream_t stream) {
  const float* x    = (const float*)d_in[0];
  const float* Wih0 = (const float*)d_in[1];
  const float* Whh0 = (const float*)d_in[2];
  const float* bih0 = (const float*)d_in[3];
  const float* bhh0 = (const float*)d_in[4];
  const float* Wih1 = (const float*)d_in[5];
  const float* Whh1 = (const float*)d_in[6];
  const float* bih1 = (const float*)d_in[7];
  const float* bhh1 = (const float*)d_in[8];
  const float* Wfc  = (const float*)d_in[9];
  const float* bfc  = (const float*)d_in[10];
  float* out = (float*)d_out;
  unsigned char* ws = (unsigned char*)d_ws;

  rnn_all<<<dim3(GRID), dim3(256), 0, stream>>>(
      x, Wih0, Whh0, bih0, bhh0, Wih1, Whh1, bih1, bhh1, Wfc, bfc, out, ws);
}